// Round 5
// baseline (250.049 us; speedup 1.0000x reference)
//
#include <hip/hip_runtime.h>

// SmoothingModule: s[t] = q[t]*s[t-1] + pe[t]*z[t] (per b,d), out masked by t < lengths[b].
//
// Single-pass decoupled-lookback chunked scan (CHUNK=16 rows/block, one launch):
//  - live block (t0 < L): z tile -> registers, local scan -> (A_c, S_c[d]);
//    publish aggregate (state=1, agent-scope release). Walk predecessors backward
//    (4-wide batches, wave shfl of flag snapshots) accumulating carry from
//    aggregates until a published inclusive prefix (state=2) terminates the walk.
//    Publish own prefix A_c*carry+S_c (only if successor chunk is live), replay
//    scan from registers, nontemporal store with per-row mask.
//  - fully-masked block (t0 >= L): write zeros, exit. Never published, never read
//    (a live walker c only reads cp < c, and cp < c_live => chunk cp fully live).
// Deadlock-free: grid B*NC <= 2048 blocks of 128 thr co-resident on 256 CUs
// (launch_bounds caps VGPR); waiters only wait on lower-indexed live blocks.
// state[] zeroed per-iteration via 4KB hipMemsetAsync (ws is re-poisoned).
// Fast path needs D==512 (D4==128). Fallback: verified 2-kernel path (round 3).

#define CHUNK 16

// clang ext_vector: __builtin_nontemporal_* accepts these (HIP float4 is rejected)
typedef float f4 __attribute__((ext_vector_type(4)));

__global__ __launch_bounds__(128, 2) void k_scan(
    const float* __restrict__ z, const float* __restrict__ P,
    const int* __restrict__ lengths,
    int* __restrict__ state, float* __restrict__ Apub,
    float* __restrict__ Sagg, float* __restrict__ Pfx,
    float* __restrict__ out, int B, int T, int NC) {
  const int blk = blockIdx.x;
  const int b = blk / NC, c = blk % NC;
  const int t0 = c * CHUNK;
  const int tid = threadIdx.x;  // == d4 column, D4 = 128
  const int L = lengths[b];
  const int nt = min(CHUNK, T - t0);
  const f4 zero = {0.f, 0.f, 0.f, 0.f};
  f4* o4 = (f4*)out;
  const size_t rowbase = ((size_t)b * T + t0) * 128;

  if (t0 >= L) {  // fully masked: zeros out, exit
    for (int t = 0; t < nt; ++t)
      __builtin_nontemporal_store(zero, &o4[rowbase + (size_t)t * 128 + tid]);
    return;
  }

  const int nlive = min(nt, L - t0);  // >= 1 here

  __shared__ float p_s[CHUNK], q_s[CHUNK];
  if (tid < CHUNK) {
    float p = (tid < nlive) ? P[(size_t)b * T + t0 + tid] : 0.0f;
    p = fminf(fmaxf(p, 0.0f), 1.0f - 1e-6f);
    q_s[tid] = 1.0f - p;
    p_s[tid] = fmaxf(p, 1e-6f);
  }
  __syncthreads();

  // ---- local scan, z tile in registers ----
  const f4* z4 = (const f4*)z;
  f4 zr[CHUNK];
#pragma unroll
  for (int t = 0; t < CHUNK; ++t)
    if (t < nlive)
      zr[t] = __builtin_nontemporal_load(&z4[rowbase + (size_t)t * 128 + tid]);
  f4 s = zero;
  float a = 1.0f;
#pragma unroll
  for (int t = 0; t < CHUNK; ++t)
    if (t < nlive) {
      float q = q_s[t], pe = p_s[t];
      s.x = fmaf(q, s.x, pe * zr[t].x);
      s.y = fmaf(q, s.y, pe * zr[t].y);
      s.z = fmaf(q, s.z, pe * zr[t].z);
      s.w = fmaf(q, s.w, pe * zr[t].w);
      a *= q;  // wave-uniform
    }

  const int idx = b * NC + c;
  const bool next_live = (t0 + CHUNK < L) && (c + 1 < NC);  // someone will read us
  f4* Sg4 = (f4*)Sagg;
  f4* Pf4 = (f4*)Pfx;

  // ---- publish aggregate (only if a live successor exists) ----
  if (c > 0 && next_live) {
    Sg4[(size_t)idx * 128 + tid] = s;
    if (tid == 0) Apub[idx] = a;
    __syncthreads();  // drains vmem (compiler emits vmcnt(0) before barrier)
    if (tid == 0) {
      __threadfence();
      __hip_atomic_store(&state[idx], 1, __ATOMIC_RELEASE, __HIP_MEMORY_SCOPE_AGENT);
    }
  }

  // ---- decoupled lookback ----
  f4 carry = zero;
  if (c > 0) {
    const int base = b * NC;
    const int lane = tid & 63;
    const f4* Sg4c = (const f4*)Sagg;
    const f4* Pf4c = (const f4*)Pfx;
    float W = 1.0f;
    int cp = c - 1;
    for (;;) {
      int nb = (cp >= 3) ? 4 : (cp + 1);
      int off = (lane < nb) ? lane : 0;
      int stv = __hip_atomic_load(&state[base + cp - off], __ATOMIC_ACQUIRE,
                                  __HIP_MEMORY_SCOPE_AGENT);
      int s0 = __shfl(stv, 0);
      if (s0 == 0) continue;  // oldest needed slot not ready: retry
      int st1 = (nb > 1) ? __shfl(stv, 1) : 0;
      int st2 = (nb > 2) ? __shfl(stv, 2) : 0;
      int st3 = (nb > 3) ? __shfl(stv, 3) : 0;
      int k = 1;
      if (st1 != 0) { k = 2; if (st2 != 0) { k = 3; if (st3 != 0) k = 4; } }
      int m = -1;  // first prefix-ready slot in walk order
      if (s0 == 2) m = 0;
      else if (k > 1 && st1 == 2) m = 1;
      else if (k > 2 && st2 == 2) m = 2;
      else if (k > 3 && st3 == 2) m = 3;
      int stop = (m >= 0) ? m : (k - 1);
      float av = Apub[base + cp - off];  // ordered after this lane's acquire
      float aa[4];
      aa[0] = __shfl(av, 0); aa[1] = __shfl(av, 1);
      aa[2] = __shfl(av, 2); aa[3] = __shfl(av, 3);
      f4 rr[4];
#pragma unroll
      for (int i = 0; i < 4; ++i) {
        int ii = (i <= stop) ? i : stop;  // clamp (duplicate loads are harmless)
        size_t ro = (size_t)(base + cp - ii) * 128 + tid;
        rr[i] = (ii == m) ? Pf4c[ro] : Sg4c[ro];
      }
      bool fin = false;
#pragma unroll
      for (int i = 0; i < 4; ++i) {
        if (i <= stop && !fin) {
          carry.x = fmaf(W, rr[i].x, carry.x);
          carry.y = fmaf(W, rr[i].y, carry.y);
          carry.z = fmaf(W, rr[i].z, carry.z);
          carry.w = fmaf(W, rr[i].w, carry.w);
          if (i == m) fin = true;
          else W *= aa[i];
        }
      }
      if (fin) break;
      cp -= k;
      if (cp < 0) break;
    }
  }

  // ---- publish inclusive prefix for successors ----
  if (next_live) {
    f4 f;
    f.x = fmaf(a, carry.x, s.x);
    f.y = fmaf(a, carry.y, s.y);
    f.z = fmaf(a, carry.z, s.z);
    f.w = fmaf(a, carry.w, s.w);
    Pf4[(size_t)idx * 128 + tid] = f;
    __syncthreads();
    if (tid == 0) {
      __threadfence();
      __hip_atomic_store(&state[idx], 2, __ATOMIC_RELEASE, __HIP_MEMORY_SCOPE_AGENT);
    }
  }

  // ---- replay from registers, masked store ----
  f4 sc = carry;
#pragma unroll
  for (int t = 0; t < CHUNK; ++t) {
    if (t < nlive) {
      float q = q_s[t], pe = p_s[t];
      sc.x = fmaf(q, sc.x, pe * zr[t].x);
      sc.y = fmaf(q, sc.y, pe * zr[t].y);
      sc.z = fmaf(q, sc.z, pe * zr[t].z);
      sc.w = fmaf(q, sc.w, pe * zr[t].w);
      __builtin_nontemporal_store(sc, &o4[rowbase + (size_t)t * 128 + tid]);
    } else if (t < nt) {
      __builtin_nontemporal_store(zero, &o4[rowbase + (size_t)t * 128 + tid]);
    }
  }
}

// ---------------- fallback 2-kernel path (verified round 3) ----------------

__global__ __launch_bounds__(128) void k_local(
    const float* __restrict__ z, const float* __restrict__ P,
    const int* __restrict__ lengths,
    float* __restrict__ S, float* __restrict__ A,
    float* __restrict__ out, int B, int T, int D4, int NC) {
  const int blk = blockIdx.x;
  const int b = blk / NC, c = blk % NC;
  const int t0 = c * CHUNK;
  const int tid = threadIdx.x;
  const int L = lengths[b];
  const int nt = min(CHUNK, T - t0);
  const float4 zero = make_float4(0.f, 0.f, 0.f, 0.f);
  const size_t rowbase = ((size_t)b * T + t0) * D4;

  if (t0 >= L) {
    float4* o4 = (float4*)out;
    if (tid < D4)
      for (int t = 0; t < nt; ++t) o4[rowbase + (size_t)t * D4 + tid] = zero;
    return;
  }
  __shared__ float p_s[CHUNK], q_s[CHUNK];
  if (tid < CHUNK) {
    int tg = t0 + tid;
    float p = (tg < T) ? P[(size_t)b * T + tg] : 0.0f;
    p = fminf(fmaxf(p, 0.0f), 1.0f - 1e-6f);
    q_s[tid] = 1.0f - p;
    p_s[tid] = fmaxf(p, 1e-6f);
  }
  __syncthreads();
  if (tid < D4) {
    const float4* z4 = (const float4*)z;
    float4 s = zero;
#pragma unroll
    for (int t = 0; t < CHUNK; ++t)
      if (t < nt) {
        float4 zv = z4[rowbase + (size_t)t * D4 + tid];
        float q = q_s[t], pe = p_s[t];
        s.x = fmaf(q, s.x, pe * zv.x);
        s.y = fmaf(q, s.y, pe * zv.y);
        s.z = fmaf(q, s.z, pe * zv.z);
        s.w = fmaf(q, s.w, pe * zv.w);
      }
    ((float4*)S)[((size_t)b * NC + c) * D4 + tid] = s;
  }
  if (tid == 0) {
    float r = 1.0f;
    for (int t = 0; t < nt; ++t) r *= q_s[t];
    A[b * NC + c] = r;
  }
}

__global__ __launch_bounds__(128) void k_apply(
    const float* __restrict__ z, const float* __restrict__ P,
    const float* __restrict__ S, const float* __restrict__ A,
    const int* __restrict__ lengths, float* __restrict__ out,
    int B, int T, int D4, int NC) {
  const int blk = blockIdx.x;
  const int b = blk / NC, c = blk % NC;
  const int t0 = c * CHUNK;
  const int tid = threadIdx.x;
  const int L = lengths[b];
  if (t0 >= L) return;
  const int nt = min(CHUNK, T - t0);
  const float4 zero = make_float4(0.f, 0.f, 0.f, 0.f);

  __shared__ float p_s[CHUNK], q_s[CHUNK];
  __shared__ float a_s[256];
  __shared__ float w_s[256];

  if (tid < CHUNK) {
    int tg = t0 + tid;
    float p = (tg < T) ? P[(size_t)b * T + tg] : 0.0f;
    p = fminf(fmaxf(p, 0.0f), 1.0f - 1e-6f);
    q_s[tid] = 1.0f - p;
    p_s[tid] = fmaxf(p, 1e-6f);
  }
  for (int i = tid; i < NC && i < 256; i += 128) a_s[i] = A[b * NC + i];
  __syncthreads();
  {
    int i0 = tid, i1 = tid + 128;
    w_s[i0] = (i0 < c - 1) ? a_s[i0 + 1] : 1.0f;
    w_s[i1] = (i1 < c - 1) ? a_s[i1 + 1] : 1.0f;
    __syncthreads();
#pragma unroll
    for (int off = 1; off < 256; off <<= 1) {
      float v0 = (i0 + off < 256) ? w_s[i0 + off] : 1.0f;
      float v1 = (i1 + off < 256) ? w_s[i1 + off] : 1.0f;
      __syncthreads();
      w_s[i0] *= v0;
      w_s[i1] *= v1;
      __syncthreads();
    }
  }
  if (tid < D4) {
    const float4* S4 = (const float4*)S + (size_t)b * NC * D4 + tid;
    float4 a0 = zero, a1 = zero, a2 = zero, a3 = zero;
    int cp = 0;
    for (; cp + 4 <= c; cp += 4) {
      float w0 = w_s[cp], w1 = w_s[cp + 1], w2 = w_s[cp + 2], w3 = w_s[cp + 3];
      float4 r0 = S4[(size_t)cp * D4];
      float4 r1 = S4[(size_t)(cp + 1) * D4];
      float4 r2 = S4[(size_t)(cp + 2) * D4];
      float4 r3 = S4[(size_t)(cp + 3) * D4];
      a0.x = fmaf(w0, r0.x, a0.x); a0.y = fmaf(w0, r0.y, a0.y);
      a0.z = fmaf(w0, r0.z, a0.z); a0.w = fmaf(w0, r0.w, a0.w);
      a1.x = fmaf(w1, r1.x, a1.x); a1.y = fmaf(w1, r1.y, a1.y);
      a1.z = fmaf(w1, r1.z, a1.z); a1.w = fmaf(w1, r1.w, a1.w);
      a2.x = fmaf(w2, r2.x, a2.x); a2.y = fmaf(w2, r2.y, a2.y);
      a2.z = fmaf(w2, r2.z, a2.z); a2.w = fmaf(w2, r2.w, a2.w);
      a3.x = fmaf(w3, r3.x, a3.x); a3.y = fmaf(w3, r3.y, a3.y);
      a3.z = fmaf(w3, r3.z, a3.z); a3.w = fmaf(w3, r3.w, a3.w);
    }
    for (; cp < c; ++cp) {
      float w = w_s[cp];
      float4 r = S4[(size_t)cp * D4];
      a0.x = fmaf(w, r.x, a0.x); a0.y = fmaf(w, r.y, a0.y);
      a0.z = fmaf(w, r.z, a0.z); a0.w = fmaf(w, r.w, a0.w);
    }
    float4 s;
    s.x = (a0.x + a1.x) + (a2.x + a3.x);
    s.y = (a0.y + a1.y) + (a2.y + a3.y);
    s.z = (a0.z + a1.z) + (a2.z + a3.z);
    s.w = (a0.w + a1.w) + (a2.w + a3.w);
    const size_t rowbase = ((size_t)b * T + t0) * D4;
    const float4* z4 = (const float4*)z;
    float4* o4 = (float4*)out;
#pragma unroll
    for (int t = 0; t < CHUNK; ++t)
      if (t < nt) {
        float4 zv = z4[rowbase + (size_t)t * D4 + tid];
        float q = q_s[t], pe = p_s[t];
        s.x = fmaf(q, s.x, pe * zv.x);
        s.y = fmaf(q, s.y, pe * zv.y);
        s.z = fmaf(q, s.z, pe * zv.z);
        s.w = fmaf(q, s.w, pe * zv.w);
        float4 o = ((t0 + t) < L) ? s : zero;
        o4[rowbase + (size_t)t * D4 + tid] = o;
      }
  }
}

extern "C" void kernel_launch(void* const* d_in, const int* in_sizes, int n_in,
                              void* d_out, int out_size, void* d_ws, size_t ws_size,
                              hipStream_t stream) {
  const float* z = (const float*)d_in[0];
  const float* P = (const float*)d_in[1];
  const int* lengths = (const int*)d_in[2];
  float* out = (float*)d_out;

  int B = in_sizes[2];
  int T = in_sizes[1] / B;
  int D = in_sizes[0] / in_sizes[1];
  int NC = (T + CHUNK - 1) / CHUNK;  // 256 for T=4096
  int D4 = D >> 2;                   // 128 for D=512
  size_t nidx = (size_t)B * NC;
  size_t nidx4 = (nidx + 3) & ~(size_t)3;

  // ws layout: state[int, nidx] | Apub[nidx] | Sagg[nidx*D] | Pfx[nidx*D]
  int* state = (int*)d_ws;
  float* Apub = (float*)d_ws + nidx4;
  float* Sagg = Apub + nidx4;
  float* Pfx = Sagg + nidx * D;
  size_t need = (nidx4 * 2 + nidx * (size_t)D * 2) * sizeof(float);

  if (D4 == 128 && nidx >= 1 && nidx <= 2048 && ws_size >= need) {
    (void)hipMemsetAsync(state, 0, nidx * sizeof(int), stream);
    k_scan<<<dim3((int)nidx), dim3(128), 0, stream>>>(
        z, P, lengths, state, Apub, Sagg, Pfx, out, B, T, NC);
    return;
  }

  // fallback (requires D4<=128, NC<=256): verified 2-kernel path
  float* S = (float*)d_ws;
  float* A = S + nidx * D;
  dim3 grid((int)nidx), block(128);
  k_local<<<grid, block, 0, stream>>>(z, P, lengths, S, A, out, B, T, D4, NC);
  k_apply<<<grid, block, 0, stream>>>(z, P, S, A, lengths, out, B, T, D4, NC);
}

// Round 6
// 93.725 us; speedup vs baseline: 2.6679x; 2.6679x over previous
//
#include <hip/hip_runtime.h>

// SmoothingModule: s[t] = q[t]*s[t-1] + pe[t]*z[t] (per b,d), out masked by t < lengths[b].
//
// Two kernels (round-0 skeleton + fixes), CHUNK=64 rows/block, 512 thr = 4 groups x 128 f4-cols:
//  k_local: live chunk -> 4 group scans (16 rows each, z in registers) -> LDS affine
//           combine -> chunk aggregate S[b,c,:], A[b,c] (stored only if successor chunk
//           is live). Fully-masked chunk (t0 >= L): write output zeros, skip z.
//  k_apply: wave0: suffix products of A row via 6-step __shfl_down scan -> LDS.
//           carry[col] = sum_{cp<c} W[cp]*S[b,cp,col], dot split over 4 groups
//           (S is 512KB -> L2-resident). Group-local scan from registers, compose
//           carry through lower groups, replay, nontemporal masked store.
// No atomics / grid sync / memset. Lookback work is O(NC^2 * D) = 16.8 MB of L2 traffic
// at NC=64 (vs 268 MB at NC=256 in round 3 -- that was the round-3 regression).
// Fast path: D==512 (128 f4 cols), NC<=64 (T<=4096). Fallback: verified round-3 path.

#define CHUNK 64
#define GR 16
#define NG 4
#define NCMAX 64

#define FB_CHUNK 16
#define FB_NCMAX 256

typedef float f4 __attribute__((ext_vector_type(4)));

__global__ __launch_bounds__(512) void kl64(
    const float* __restrict__ z, const float* __restrict__ P,
    const int* __restrict__ lengths,
    float* __restrict__ S, float* __restrict__ A,
    float* __restrict__ out, int B, int T, int NC) {
  const int blk = blockIdx.x;
  const int b = blk / NC, c = blk % NC;
  const int t0 = c * CHUNK;
  const int tid = threadIdx.x;
  const int col = tid & 127, g = tid >> 7;
  const int L = lengths[b];
  const int nt = min(CHUNK, T - t0);
  const f4 zero = {0.f, 0.f, 0.f, 0.f};
  f4* o4 = (f4*)out;
  const size_t rowbase = ((size_t)b * T + t0) * 128;

  if (t0 >= L) {  // fully masked: zeros to out, skip z entirely
    for (int r = g; r < nt; r += NG)
      __builtin_nontemporal_store(zero, &o4[rowbase + (size_t)r * 128 + col]);
    return;
  }

  __shared__ float p_s[CHUNK], q_s[CHUNK];
  __shared__ float ga_s[NG];
  __shared__ f4 gs_s[NG][128];

  if (tid < CHUNK) {
    int tg = t0 + tid;
    float p = (tg < T) ? P[(size_t)b * T + tg] : 0.0f;
    p = fminf(fmaxf(p, 0.0f), 1.0f - 1e-6f);
    q_s[tid] = 1.0f - p;
    p_s[tid] = fmaxf(p, 1e-6f);
  }
  __syncthreads();

  const int r0 = g * GR;
  const int ng = min(GR, nt - r0);  // may be <= 0 on tail chunks
  const f4* z4 = (const f4*)z;
  f4 zr[GR];
#pragma unroll
  for (int j = 0; j < GR; ++j)
    if (j < ng) zr[j] = z4[rowbase + (size_t)(r0 + j) * 128 + col];
  f4 s = zero;
  float a = 1.0f;
#pragma unroll
  for (int j = 0; j < GR; ++j)
    if (j < ng) {
      float q = q_s[r0 + j], pe = p_s[r0 + j];
      s.x = fmaf(q, s.x, pe * zr[j].x);
      s.y = fmaf(q, s.y, pe * zr[j].y);
      s.z = fmaf(q, s.z, pe * zr[j].z);
      s.w = fmaf(q, s.w, pe * zr[j].w);
      a *= q;
    }
  gs_s[g][col] = s;
  if (col == 0) ga_s[g] = a;
  __syncthreads();

  // publish chunk aggregate only if a live successor will read it
  if ((t0 + CHUNK < L) && (c + 1 < NC)) {
    if (g == NG - 1) {
      f4 x = gs_s[0][col];
#pragma unroll
      for (int j = 1; j < NG; ++j) {
        float aj = ga_s[j];
        f4 sj = gs_s[j][col];
        x.x = fmaf(aj, x.x, sj.x);
        x.y = fmaf(aj, x.y, sj.y);
        x.z = fmaf(aj, x.z, sj.z);
        x.w = fmaf(aj, x.w, sj.w);
      }
      ((f4*)S)[((size_t)b * NC + c) * 128 + col] = x;
    }
    if (tid == 0) A[b * NC + c] = ga_s[0] * ga_s[1] * ga_s[2] * ga_s[3];
  }
}

__global__ __launch_bounds__(512) void ka64(
    const float* __restrict__ z, const float* __restrict__ P,
    const float* __restrict__ S, const float* __restrict__ A,
    const int* __restrict__ lengths, float* __restrict__ out,
    int B, int T, int NC) {
  const int blk = blockIdx.x;
  const int b = blk / NC, c = blk % NC;
  const int t0 = c * CHUNK;
  const int tid = threadIdx.x;
  const int col = tid & 127, g = tid >> 7;
  const int L = lengths[b];
  if (t0 >= L) return;  // kl64 wrote the zeros
  const int nt = min(CHUNK, T - t0);
  const f4 zero = {0.f, 0.f, 0.f, 0.f};

  __shared__ float p_s[CHUNK], q_s[CHUNK];
  __shared__ float sp_s[NCMAX + 1];  // sp_s[k] = prod_{j>=k} y[j], y[j]=A[j] (j<c) else 1
  __shared__ float ga_s[NG];
  __shared__ f4 gs_s[NG][128];
  __shared__ f4 part_s[NG][128];

  // issue z tile -> registers early (L3-warm from kl64)
  const int r0 = g * GR;
  const int ng = min(GR, nt - r0);
  const f4* z4 = (const f4*)z;
  const size_t rowbase = ((size_t)b * T + t0) * 128;
  f4 zr[GR];
#pragma unroll
  for (int j = 0; j < GR; ++j)
    if (j < ng) zr[j] = z4[rowbase + (size_t)(r0 + j) * 128 + col];

  if (tid < CHUNK) {
    int tg = t0 + tid;
    float p = (tg < T) ? P[(size_t)b * T + tg] : 0.0f;
    p = fminf(fmaxf(p, 0.0f), 1.0f - 1e-6f);
    q_s[tid] = 1.0f - p;
    p_s[tid] = fmaxf(p, 1e-6f);
  }
  // wave 0: suffix products of the A row (6-step shfl scan, no serial chain)
  if (tid < 64) {
    const int lane = tid;
    float y = (lane < c) ? A[b * NC + lane] : 1.0f;
#pragma unroll
    for (int off = 1; off < 64; off <<= 1) {
      float t = __shfl_down(y, off);
      if (lane + off < 64) y *= t;
    }
    sp_s[lane] = y;  // = prod_{j=lane}^{63} y_init[j]
  }
  __syncthreads();

  // carry[col] = sum_{cp<c} W[cp] * S[b,cp,col], W[cp] = sp_s[cp+1]; split over groups
  f4 acc = zero;
  const f4* S4 = (const f4*)S;
  for (int cp = g; cp < c; cp += NG) {
    float w = sp_s[cp + 1];
    f4 r = S4[((size_t)b * NC + cp) * 128 + col];
    acc.x = fmaf(w, r.x, acc.x);
    acc.y = fmaf(w, r.y, acc.y);
    acc.z = fmaf(w, r.z, acc.z);
    acc.w = fmaf(w, r.w, acc.w);
  }
  part_s[g][col] = acc;

  // group-local scan from zero (for intra-block carry composition)
  f4 s = zero;
  float a = 1.0f;
#pragma unroll
  for (int j = 0; j < GR; ++j)
    if (j < ng) {
      float q = q_s[r0 + j], pe = p_s[r0 + j];
      s.x = fmaf(q, s.x, pe * zr[j].x);
      s.y = fmaf(q, s.y, pe * zr[j].y);
      s.z = fmaf(q, s.z, pe * zr[j].z);
      s.w = fmaf(q, s.w, pe * zr[j].w);
      a *= q;
    }
  gs_s[g][col] = s;
  if (col == 0) ga_s[g] = a;
  __syncthreads();

  f4 carry = part_s[0][col];
  {
    f4 p1 = part_s[1][col], p2 = part_s[2][col], p3 = part_s[3][col];
    carry.x = (carry.x + p1.x) + (p2.x + p3.x);
    carry.y = (carry.y + p1.y) + (p2.y + p3.y);
    carry.z = (carry.z + p1.z) + (p2.z + p3.z);
    carry.w = (carry.w + p1.w) + (p2.w + p3.w);
  }
  // compose carry through lower groups: x_{j+1} = ga[j]*x_j + gs[j]
#pragma unroll
  for (int j = 0; j < NG - 1; ++j)
    if (j < g) {
      float aj = ga_s[j];
      f4 sj = gs_s[j][col];
      carry.x = fmaf(aj, carry.x, sj.x);
      carry.y = fmaf(aj, carry.y, sj.y);
      carry.z = fmaf(aj, carry.z, sj.z);
      carry.w = fmaf(aj, carry.w, sj.w);
    }

  // replay from registers, masked nontemporal store
  f4* o4 = (f4*)out;
  f4 sc = carry;
#pragma unroll
  for (int j = 0; j < GR; ++j)
    if (j < ng) {
      float q = q_s[r0 + j], pe = p_s[r0 + j];
      sc.x = fmaf(q, sc.x, pe * zr[j].x);
      sc.y = fmaf(q, sc.y, pe * zr[j].y);
      sc.z = fmaf(q, sc.z, pe * zr[j].z);
      sc.w = fmaf(q, sc.w, pe * zr[j].w);
      f4 o = ((t0 + r0 + j) < L) ? sc : zero;
      __builtin_nontemporal_store(o, &o4[rowbase + (size_t)(r0 + j) * 128 + col]);
    }
}

// ---------------- fallback 2-kernel path (verified round 3) ----------------

__global__ __launch_bounds__(128) void k_local_fb(
    const float* __restrict__ z, const float* __restrict__ P,
    const int* __restrict__ lengths,
    float* __restrict__ S, float* __restrict__ A,
    float* __restrict__ out, int B, int T, int D4, int NC) {
  const int blk = blockIdx.x;
  const int b = blk / NC, c = blk % NC;
  const int t0 = c * FB_CHUNK;
  const int tid = threadIdx.x;
  const int L = lengths[b];
  const int nt = min(FB_CHUNK, T - t0);
  const float4 zero = make_float4(0.f, 0.f, 0.f, 0.f);
  const size_t rowbase = ((size_t)b * T + t0) * D4;

  if (t0 >= L) {
    float4* o4 = (float4*)out;
    if (tid < D4)
      for (int t = 0; t < nt; ++t) o4[rowbase + (size_t)t * D4 + tid] = zero;
    return;
  }
  __shared__ float p_s[FB_CHUNK], q_s[FB_CHUNK];
  if (tid < FB_CHUNK) {
    int tg = t0 + tid;
    float p = (tg < T) ? P[(size_t)b * T + tg] : 0.0f;
    p = fminf(fmaxf(p, 0.0f), 1.0f - 1e-6f);
    q_s[tid] = 1.0f - p;
    p_s[tid] = fmaxf(p, 1e-6f);
  }
  __syncthreads();
  if (tid < D4) {
    const float4* z4 = (const float4*)z;
    float4 s = zero;
#pragma unroll
    for (int t = 0; t < FB_CHUNK; ++t)
      if (t < nt) {
        float4 zv = z4[rowbase + (size_t)t * D4 + tid];
        float q = q_s[t], pe = p_s[t];
        s.x = fmaf(q, s.x, pe * zv.x);
        s.y = fmaf(q, s.y, pe * zv.y);
        s.z = fmaf(q, s.z, pe * zv.z);
        s.w = fmaf(q, s.w, pe * zv.w);
      }
    ((float4*)S)[((size_t)b * NC + c) * D4 + tid] = s;
  }
  if (tid == 0) {
    float r = 1.0f;
    for (int t = 0; t < nt; ++t) r *= q_s[t];
    A[b * NC + c] = r;
  }
}

__global__ __launch_bounds__(128) void k_apply_fb(
    const float* __restrict__ z, const float* __restrict__ P,
    const float* __restrict__ S, const float* __restrict__ A,
    const int* __restrict__ lengths, float* __restrict__ out,
    int B, int T, int D4, int NC) {
  const int blk = blockIdx.x;
  const int b = blk / NC, c = blk % NC;
  const int t0 = c * FB_CHUNK;
  const int tid = threadIdx.x;
  const int L = lengths[b];
  if (t0 >= L) return;
  const int nt = min(FB_CHUNK, T - t0);
  const float4 zero = make_float4(0.f, 0.f, 0.f, 0.f);

  __shared__ float p_s[FB_CHUNK], q_s[FB_CHUNK];
  __shared__ float a_s[FB_NCMAX];
  __shared__ float w_s[FB_NCMAX];

  if (tid < FB_CHUNK) {
    int tg = t0 + tid;
    float p = (tg < T) ? P[(size_t)b * T + tg] : 0.0f;
    p = fminf(fmaxf(p, 0.0f), 1.0f - 1e-6f);
    q_s[tid] = 1.0f - p;
    p_s[tid] = fmaxf(p, 1e-6f);
  }
  for (int i = tid; i < NC && i < FB_NCMAX; i += 128) a_s[i] = A[b * NC + i];
  __syncthreads();
  {
    int i0 = tid, i1 = tid + 128;
    w_s[i0] = (i0 < c - 1) ? a_s[i0 + 1] : 1.0f;
    w_s[i1] = (i1 < c - 1) ? a_s[i1 + 1] : 1.0f;
    __syncthreads();
#pragma unroll
    for (int off = 1; off < 256; off <<= 1) {
      float v0 = (i0 + off < 256) ? w_s[i0 + off] : 1.0f;
      float v1 = (i1 + off < 256) ? w_s[i1 + off] : 1.0f;
      __syncthreads();
      w_s[i0] *= v0;
      w_s[i1] *= v1;
      __syncthreads();
    }
  }
  if (tid < D4) {
    const float4* S4 = (const float4*)S + (size_t)b * NC * D4 + tid;
    float4 a0 = zero, a1 = zero, a2 = zero, a3 = zero;
    int cp = 0;
    for (; cp + 4 <= c; cp += 4) {
      float w0 = w_s[cp], w1 = w_s[cp + 1], w2 = w_s[cp + 2], w3 = w_s[cp + 3];
      float4 r0 = S4[(size_t)cp * D4];
      float4 r1 = S4[(size_t)(cp + 1) * D4];
      float4 r2 = S4[(size_t)(cp + 2) * D4];
      float4 r3 = S4[(size_t)(cp + 3) * D4];
      a0.x = fmaf(w0, r0.x, a0.x); a0.y = fmaf(w0, r0.y, a0.y);
      a0.z = fmaf(w0, r0.z, a0.z); a0.w = fmaf(w0, r0.w, a0.w);
      a1.x = fmaf(w1, r1.x, a1.x); a1.y = fmaf(w1, r1.y, a1.y);
      a1.z = fmaf(w1, r1.z, a1.z); a1.w = fmaf(w1, r1.w, a1.w);
      a2.x = fmaf(w2, r2.x, a2.x); a2.y = fmaf(w2, r2.y, a2.y);
      a2.z = fmaf(w2, r2.z, a2.z); a2.w = fmaf(w2, r2.w, a2.w);
      a3.x = fmaf(w3, r3.x, a3.x); a3.y = fmaf(w3, r3.y, a3.y);
      a3.z = fmaf(w3, r3.z, a3.z); a3.w = fmaf(w3, r3.w, a3.w);
    }
    for (; cp < c; ++cp) {
      float w = w_s[cp];
      float4 r = S4[(size_t)cp * D4];
      a0.x = fmaf(w, r.x, a0.x); a0.y = fmaf(w, r.y, a0.y);
      a0.z = fmaf(w, r.z, a0.z); a0.w = fmaf(w, r.w, a0.w);
    }
    float4 s;
    s.x = (a0.x + a1.x) + (a2.x + a3.x);
    s.y = (a0.y + a1.y) + (a2.y + a3.y);
    s.z = (a0.z + a1.z) + (a2.z + a3.z);
    s.w = (a0.w + a1.w) + (a2.w + a3.w);
    const size_t rowbase = ((size_t)b * T + t0) * D4;
    const float4* z4 = (const float4*)z;
    float4* o4 = (float4*)out;
#pragma unroll
    for (int t = 0; t < FB_CHUNK; ++t)
      if (t < nt) {
        float4 zv = z4[rowbase + (size_t)t * D4 + tid];
        float q = q_s[t], pe = p_s[t];
        s.x = fmaf(q, s.x, pe * zv.x);
        s.y = fmaf(q, s.y, pe * zv.y);
        s.z = fmaf(q, s.z, pe * zv.z);
        s.w = fmaf(q, s.w, pe * zv.w);
        float4 o = ((t0 + t) < L) ? s : zero;
        o4[rowbase + (size_t)t * D4 + tid] = o;
      }
  }
}

extern "C" void kernel_launch(void* const* d_in, const int* in_sizes, int n_in,
                              void* d_out, int out_size, void* d_ws, size_t ws_size,
                              hipStream_t stream) {
  const float* z = (const float*)d_in[0];
  const float* P = (const float*)d_in[1];
  const int* lengths = (const int*)d_in[2];
  float* out = (float*)d_out;

  int B = in_sizes[2];
  int T = in_sizes[1] / B;
  int D = in_sizes[0] / in_sizes[1];
  int D4 = D >> 2;

  if (D4 == 128) {
    int NC = (T + CHUNK - 1) / CHUNK;  // 64 for T=4096
    if (NC >= 1 && NC <= NCMAX) {
      // ws: S [B*NC*D] | A [B*NC]
      float* S = (float*)d_ws;
      float* A = S + (size_t)B * NC * D;
      dim3 grid(B * NC), block(512);
      kl64<<<grid, block, 0, stream>>>(z, P, lengths, S, A, out, B, T, NC);
      ka64<<<grid, block, 0, stream>>>(z, P, S, A, lengths, out, B, T, NC);
      return;
    }
  }

  // fallback (D4<=128, NC<=256): verified round-3 path
  int NC = (T + FB_CHUNK - 1) / FB_CHUNK;
  float* S = (float*)d_ws;
  float* A = S + (size_t)B * NC * D;
  dim3 grid(B * NC), block(128);
  k_local_fb<<<grid, block, 0, stream>>>(z, P, lengths, S, A, out, B, T, D4, NC);
  k_apply_fb<<<grid, block, 0, stream>>>(z, P, S, A, lengths, out, B, T, D4, NC);
}